// Round 8
// baseline (1485.428 us; speedup 1.0000x reference)
//
#include <hip/hip_runtime.h>
#include <hip/hip_bf16.h>
#include <math.h>

// CaptionModel: 200-step GRU (B=256,H=512) + projection V=100.
// Round-18 = round-17 (1420us steady) + two micro-levers:
//  (1) self-release barrier: ALL waves poll the 32 flag lines (lanes 0-63
//      map pairwise onto lines; __all over 64 lanes), NO release
//      __syncthreads. A wave that sees completion issues its 24 next-step
//      sc0 h-loads immediately (L2 latency overlaps other waves' poll exit);
//      q0-end s_barrier reconverges. Safe: all waves passed the pre-flag
//      sync, so both A-buffers' reads are complete before any early dump.
//  (2) convert kernel: 32-bit unsigned index math in the grid-stride loop
//      (TOT < 2^31) - 64-bit div/mod by 24576/8192/512 were ~20-op magic
//      sequences x 5.8M elements. Values identical.
// Everything else r17-verbatim: XCD-local L2 h-exchange (plain stores + sc0
// loads), counted per-quarter vmcnt staging, per-block flag lines.
// Ledger of measured-dead levers: r12 lc-swizzle/Gm-pad/static-proj (-4%),
// r13 arrival tree + all-thread single-line poll (-5%), r14 2 blocks/CU
// (Breg spill, -82%), r15 single vmcnt(0) (-5%), r17 flag barrier (0%).
// Canary: absmax must be exactly 0.0078125.

typedef __bf16 bf16_t;
typedef __bf16 bf16x8 __attribute__((ext_vector_type(8)));
typedef float f32x4 __attribute__((ext_vector_type(4)));
typedef unsigned long long u64;
typedef unsigned short u16;
typedef unsigned int u32;

#define B_ 256
#define H_ 512
#define V_ 100
#define T_ 200
#define NF_ 131072              // B_*H_
#define SLAB_ 24576             // per (group,jt): 3 sp * 16 c * 16 r * 32 k
#define MFMA(a,b,c) __builtin_amdgcn_mfma_f32_16x16x32_bf16((a),(b),(c),0,0,0)

__device__ __forceinline__ float ld_in(const void* p, long i, int isf32) {
    return isf32 ? ((const float*)p)[i] : (float)((const bf16_t*)p)[i];
}

__device__ __forceinline__ bf16_t split_pick(double v, int sp) {
    bf16_t a = (bf16_t)(float)v;
    if (sp == 0) return a;
    double r1 = v - (double)(float)a;
    bf16_t b = (bf16_t)(float)r1;
    if (sp == 1) return b;
    double r2 = r1 - (double)(float)b;
    return (bf16_t)(float)r2;
}

union bfbits { __bf16 b; u16 u; };

// ---------------------------------------------------------------------------
// Canonical buffers (round-8 verbatim):
//  WB [4 grp][32 jt][3 sp][16 c][16 r][32 k]  grps: Rc, Zc, NI, NH
//  W0 [3 grp][32 jt][3 sp][16 c][16 r][32 k]  wh-only (s==0)
//  PB [7 vt][2 sp][16 c][16 r][32 k]
//  hsp linear [2 pp][3 sp][m 256][col 512];  BB [4][512] f64; gi0[1536] f64
__global__ __launch_bounds__(256) void convert_kernel(
    const void* __restrict__ feat, const void* __restrict__ embed,
    const void* __restrict__ wih,  const void* __restrict__ whh,
    const void* __restrict__ bih,  const void* __restrict__ bhh,
    const void* __restrict__ pw,   const void* __restrict__ pb,
    char* __restrict__ barr, int* __restrict__ flag,
    bf16_t* __restrict__ WB, bf16_t* __restrict__ W0, bf16_t* __restrict__ PB,
    bf16_t* __restrict__ hsp, double* __restrict__ hf,
    double* __restrict__ BB, double* __restrict__ pbd, double* __restrict__ gi0)
{
    // runtime dtype detection on feat (~N(0,1)): bf16 buffer -> low u16 of a
    // u32 is a plausible bf16 (~128/128); f32 -> mantissa bits (~15/128).
    __shared__ int s_cnt;
    if (threadIdx.x == 0) s_cnt = 0;
    __syncthreads();
    if (threadIdx.x < 128) {
        unsigned w = ((const unsigned*)feat)[threadIdx.x];
        unsigned e = (w >> 7) & 0xFFu;
        if (e >= 0x68u && e <= 0x85u) atomicAdd(&s_cnt, 1);
    }
    __syncthreads();
    const int isf32 = (s_cnt < 96) ? 1 : 0;
    if (blockIdx.x == 0) {
        if (threadIdx.x == 0) *flag = isf32;
        // zero barrier state: 256 flag lines (8 mh x 32 jt) + 8 xslot lines
        if (threadIdx.x < 256)
            *(int*)(barr + (size_t)threadIdx.x * 128) = 0;
        if (threadIdx.x < 8)
            *(int*)(barr + 32768 + (size_t)threadIdx.x * 128) = 0;
    }

    const u32 S0 = NF_;
    const u32 S1 = 3145728;      // WB elems
    const u32 S2 = 2359296;      // W0
    const u32 S3 = 114688;       // PB
    const u32 S4 = 2048;         // BB
    const u32 S5 = 100;          // pbd
    const u32 S6 = 1536;         // gi0
    const u32 TOT = S0 + S1 + S2 + S3 + S4 + S5 + S6;

    for (u32 g = blockIdx.x * 256u + threadIdx.x; g < TOT;
         g += (u32)gridDim.x * 256u) {
        u32 i = g;
        if (i < S0) {
            double v = (double)ld_in(feat, i, isf32);
            hf[i] = v;
            hsp[i] = split_pick(v, 0);
            hsp[NF_ + i] = split_pick(v, 1);
            hsp[2 * NF_ + i] = split_pick(v, 2);
            continue;
        }
        i -= S0;
        if (i < S1) {
            u32 slab = i / SLAB_;  u32 rem = i % SLAB_;
            u32 grp = slab >> 5, jt = slab & 31;
            u32 sp = rem / 8192; u32 r2 = rem % 8192;
            u32 c = r2 / 512, r = (r2 % 512) / 32, kk = r2 & 31;
            u32 n = jt * 16 + r, k = c * 32 + kk;
            double v;
            if (grp == 0)      v = (double)ld_in(wih, n * H_ + k, isf32) +
                                   (double)ld_in(whh, n * H_ + k, isf32);
            else if (grp == 1) v = (double)ld_in(wih, (512 + n) * H_ + k, isf32) +
                                   (double)ld_in(whh, (512 + n) * H_ + k, isf32);
            else if (grp == 2) v = (double)ld_in(wih, (1024 + n) * H_ + k, isf32);
            else               v = (double)ld_in(whh, (1024 + n) * H_ + k, isf32);
            WB[i] = split_pick(v, sp);
            continue;
        }
        i -= S1;
        if (i < S2) {
            u32 slab = i / SLAB_;  u32 rem = i % SLAB_;
            u32 grp = slab >> 5, jt = slab & 31;
            u32 sp = rem / 8192; u32 r2 = rem % 8192;
            u32 c = r2 / 512, r = (r2 % 512) / 32, kk = r2 & 31;
            u32 n = jt * 16 + r, k = c * 32 + kk;
            u32 row = (grp == 0) ? n : (grp == 1) ? (512 + n) : (1024 + n);
            W0[i] = split_pick((double)ld_in(whh, row * H_ + k, isf32), sp);
            continue;
        }
        i -= S2;
        if (i < S3) {
            u32 vt = i / 16384; u32 rem = i % 16384;
            u32 sp = rem / 8192; u32 r2 = rem % 8192;
            u32 c = r2 / 512, r = (r2 % 512) / 32, kk = r2 & 31;
            u32 v = vt * 16 + r;
            u32 k = c * 32 + kk;
            double val = (v < V_) ? (double)ld_in(pw, (long)(v * H_ + k), isf32) : 0.0;
            PB[i] = split_pick(val, sp);
            continue;
        }
        i -= S3;
        if (i < S4) {
            u32 grp = i / 512, j = i & 511;
            double v;
            if (grp == 0)      v = (double)ld_in(bih, j, isf32) + (double)ld_in(bhh, j, isf32);
            else if (grp == 1) v = (double)ld_in(bih, 512 + j, isf32) + (double)ld_in(bhh, 512 + j, isf32);
            else if (grp == 2) v = (double)ld_in(bih, 1024 + j, isf32);
            else               v = (double)ld_in(bhh, 1024 + j, isf32);
            BB[i] = v;
            continue;
        }
        i -= S4;
        if (i < S5) { pbd[i] = (double)ld_in(pb, i, isf32); continue; }
        i -= S5;
        if (i < S6) {
            double acc = 0.0;
            #pragma unroll 8
            for (u32 k = 0; k < H_; ++k)
                acc += (double)ld_in(embed, k, isf32) *
                       (double)ld_in(wih, i * H_ + k, isf32);
            gi0[i] = acc;
        }
    }
}

// per-quarter tied wait: ds_writes of these 6 regs depend on this asm's
// outputs, so they cannot be scheduled above it (consumers are memory ops).
#define WAITQ(N, s0, s1, s2, s3, s4, s5)                                   \
    asm volatile("s_waitcnt vmcnt(" #N ")"                                 \
                 : "+v"(s0), "+v"(s1), "+v"(s2), "+v"(s3), "+v"(s4),       \
                   "+v"(s5) :: "memory")

// ---------------------------------------------------------------------------
// Persistent: 256 blocks x 512 threads (8 waves = 2/SIMD), 1 block/CU.
// mh = physical XCD (s_getreg HW_REG_XCC_ID), jt = per-XCD atomic slot 0..31
// (exactly 32 blocks/XCD by pigeonhole: 1 block/CU, 32 CU/XCD). The whole
// h-exchange for an mh-group is XCD-local: plain stores (L2-cached),
// sc0 loads (L1-bypass, read own L2). Barrier: per-block flag lines +
// ALL-wave 32-line parallel poll, self-release (no release sync; q0-end
// s_barrier reconverges). Structure r11-verbatim.
__global__ __launch_bounds__(512, 2) void gru_persist(
    const bf16_t* __restrict__ WB, const bf16_t* __restrict__ W0,
    const bf16_t* __restrict__ PB,
    bf16_t* __restrict__ hsp,      // [2 pp][3 sp][NF_] linear
    const double* __restrict__ hf, // initial h (f64)
    const double* __restrict__ BB, const double* __restrict__ pbd,
    const double* __restrict__ gi0,
    const int* __restrict__ flag, char* __restrict__ barr,
    void* __restrict__ outp)
{
    __shared__ __align__(16) u64 Ad[2][3072];     // 49,152 B: A dbuf (2 quarters)
    __shared__ double Gm[8][32][16];              // 32,768 B
    __shared__ __align__(16) bf16_t PBl[16384];   // 32,768 B: proj B slab
    __shared__ int s_slot;
    // total ~114,696 B static LDS (gfx950: 160 KB/CU, 1 block/CU)

    const int tid = threadIdx.x;
    const int w = tid >> 6;
    const int g = w & 3;
    const int par = w >> 2;
    const int lane = tid & 63;
    const int ln = lane & 15;
    const int quad = lane >> 4;

    // physical XCD id (wave-uniform; m09-verified 0..7 on MI355X)
    unsigned xcc;
    asm volatile("s_getreg_b32 %0, hwreg(HW_REG_XCC_ID)" : "=s"(xcc));
    xcc &= 7u;
    if (tid == 0) {
        int* xslot = (int*)(barr + 32768 + (size_t)xcc * 128);
        s_slot = __hip_atomic_fetch_add(xslot, 1, __ATOMIC_RELAXED,
                                        __HIP_MEMORY_SCOPE_AGENT);
    }
    __syncthreads();
    const int jt = s_slot & 31;      // unique 0..31 within this XCD
    const int mh = (int)xcc;         // mh-group == XCD -> L2-local exchange
    const int m0base = mh * 32;
    const int isf32 = *flag;

    // barrier flag lines: per mh, 32 lines of 128 B; each lane polls line
    // (lane&31) -> lanes 0..63 cover the 32 lines pairwise, __all over 64.
    int* const flagbase = (int*)(barr + (size_t)mh * 4096);
    int* const myflag   = flagbase + (size_t)jt * 32;
    int* const pollp    = flagbase + (size_t)(lane & 31) * 32;

    // gate-phase ownership + step-invariant hoists (round-8 verbatim)
    const int gm = tid >> 4;
    const int gj = tid & 15;
    const int jg = jt * 16 + gj;
    double hreg = hf[(long)(m0base + gm) * H_ + jg];
    const double bbR = BB[jg], bbZ = BB[512 + jg];
    const double bbNI = BB[1024 + jg], bbNH = BB[1536 + jg];
    const double g0R = gi0[jg], g0Z = gi0[512 + jg], g0NI = gi0[1024 + jg];

    // weight fragments in registers: Breg[n][sp], chunk c = par + 2n
    bf16x8 Breg[8][3];
    {
        const int gg = (g == 3) ? 2 : g;          // s==0 slab (g==2 unused)
        const bf16_t* wpre = W0 + (long)(gg * 32 + jt) * SLAB_ + ln * 32 + quad * 8;
        #pragma unroll
        for (int n = 0; n < 8; ++n)
            #pragma unroll
            for (int sp = 0; sp < 3; ++sp)
                Breg[n][sp] = *(const bf16x8*)(wpre + sp * 8192 + (par + 2 * n) * 512);
    }
    const bf16_t* wpW = WB + (long)(g * 32 + jt) * SLAB_ + ln * 32 + quad * 8;

    const int tpj = jt & 1;

    // one-time PB slab -> LDS, fragment-linear: chunk j (8 bf16) of c-block
    // goes to slot L(j) = (j&3)*16 + (j>>2), so the doproj read of lane L is
    // a dense 16B at PBl + h01*8192 + c*512 + L*8 (conflict-free b128).
    if (jt < 14) {
        const bf16_t* src = PB + (long)(jt >> 1) * 16384;
        #pragma unroll
        for (int it = 0; it < 4; ++it) {
            int cg = it * 512 + tid;              // 2048 16B-chunks total
            int h01 = cg >> 10, c = (cg >> 6) & 15, j = cg & 63;
            int L = (j & 3) * 16 + (j >> 2);
            *(bf16x8*)(PBl + h01 * 8192 + c * 512 + L * 8) =
                *(const bf16x8*)(src + cg * 8);
        }
    }

    // swizzled element offset for this lane's A-fragment reads (parity XOR
    // matches the dump lpos; r = ln recovered since x^((x&1)<<2) is injective)
    const int lf = (((ln ^ quad) ^ ((ln & 1) << 2)) | (quad << 4)) * 8;

    // step-invariant staging addresses: thread's 6 elements per quarter.
    // load pattern (coalesced 512B/wave) is round-8 verbatim.
    int soff[6]; int ldst[6];
    #pragma unroll
    for (int i = 0; i < 6; ++i) {
        int u = i * 512 + tid;
        int sp = u >> 10, row = (u >> 5) & 31, k64 = u & 31;
        soff[i] = sp * 32768 + (m0base + row) * 128 + k64;
        int lc = k64 >> 3, qd = (k64 & 7) >> 1, half = k64 & 1;
        int lpos = (((row & 15) ^ qd) ^ ((row & 1) << 2)) | (qd << 4);
        ldst[i] = sp * 1024 + lc * 256 + (row >> 4) * 128 + lpos * 2 + half;
    }
    __syncthreads();     // PBl staged before any use

    for (int s = 0; s <= T_; ++s) {
        const u64* hin64 = (const u64*)(hsp + (long)(s & 1) * 3 * NF_);
        const bool gemm = (s < T_) && !(s == 0 && g == 2);
        const bool doproj = (s >= 1 && jt < 14 && w == (s & 7));

        double dg0[4] = {0, 0, 0, 0}, dg1[4] = {0, 0, 0, 0};
        f32x4 pacc = {0.f, 0.f, 0.f, 0.f};

        // all 24 h-loads issued up-front via sc0 (L1-bypass, own-XCD L2 hit),
        // in quarter order; counted vmcnt waits below keep later quarters in
        // flight under earlier quarters' dump+MFMA (r11-style pipelining).
        u64 sreg[24];
        #pragma unroll
        for (int qq = 0; qq < 4; ++qq)
            #pragma unroll
            for (int i = 0; i < 6; ++i) {
                const u64* p = hin64 + (long)soff[i] + qq * 32;
                asm volatile("global_load_dwordx2 %0, %1, off sc0"
                             : "=v"(sreg[qq * 6 + i]) : "v"(p));
            }

        // dump quarter 0 -> buf0 (wait only its 6 loads: 18 may remain)
        WAITQ(18, sreg[0], sreg[1], sreg[2], sreg[3], sreg[4], sreg[5]);
        #pragma unroll
        for (int i = 0; i < 6; ++i) Ad[0][ldst[i]] = sreg[i];
        __syncthreads();

        #pragma unroll
        for (int q = 0; q < 4; ++q) {
            if (q < 3) {     // dump q+1 into the other buffer (overlaps compute)
                if (q == 0)
                    WAITQ(12, sreg[6], sreg[7], sreg[8], sreg[9], sreg[10], sreg[11]);
                else if (q == 1)
                    WAITQ(6, sreg[12], sreg[13], sreg[14], sreg[15], sreg[16], sreg[17]);
                else
                    WAITQ(0, sreg[18], sreg[19], sreg[20], sreg[21], sreg[22], sreg[23]);
                #pragma unroll
                for (int i = 0; i < 6; ++i)
                    Ad[(q + 1) & 1][ldst[i]] = sreg[(q + 1) * 6 + i];
            }
            const __bf16* Ab = (const __bf16*)(Ad[q & 1]);

            if (gemm) {
                #pragma unroll
                for (int t = 0; t < 2; ++t) {
                    const int lc = 2 * t + par;
                    const int n = 2 * q + t;
                    bf16x8 A0[3], A1[3];
                    #pragma unroll
                    for (int sp = 0; sp < 3; ++sp) {
                        A0[sp] = *(const bf16x8*)(Ab + sp * 4096 + lc * 1024 + lf);
                        A1[sp] = *(const bf16x8*)(Ab + sp * 4096 + lc * 1024 + 512 + lf);
                    }
                    f32x4 t0 = {0.f, 0.f, 0.f, 0.f};
                    t0 = MFMA(A0[0], Breg[n][2], t0);
                    t0 = MFMA(A0[1], Breg[n][1], t0);
                    t0 = MFMA(A0[2], Breg[n][0], t0);
                    t0 = MFMA(A0[0], Breg[n][1], t0);
                    t0 = MFMA(A0[1], Breg[n][0], t0);
                    t0 = MFMA(A0[0], Breg[n][0], t0);
                    f32x4 t1 = {0.f, 0.f, 0.f, 0.f};
                    t1 = MFMA(A1[0], Breg[n][2], t1);
                    t1 = MFMA(A1[1], Breg[n][1], t1);
                    t1 = MFMA(A1[2], Breg[n][0], t1);
                    t1 = MFMA(A1[0], Breg[n][1], t1);
                    t1 = MFMA(A1[1], Breg[n][0], t1);
                    t1 = MFMA(A1[0], Breg[n][0], t1);
                    #pragma unroll
                    for (int i = 0; i < 4; ++i) {
                        dg0[i] += (double)t0[i];
                        dg1[i] += (double)t1[i];
                    }
                }
            }
            if (doproj) {
                #pragma unroll
                for (int lc = 0; lc < 4; ++lc) {   // ascending c: bit-exact
                    const int c = q * 4 + lc;
                    bf16x8 pa1 = *(const bf16x8*)(Ab + 0 * 4096 + lc * 1024 + tpj * 512 + lf);
                    bf16x8 pa2 = *(const bf16x8*)(Ab + 1 * 4096 + lc * 1024 + tpj * 512 + lf);
                    bf16x8 b1v = *(const bf16x8*)(PBl + c * 512 + lane * 8);
                    bf16x8 b2v = *(const bf16x8*)(PBl + 8192 + c * 512 + lane * 8);
                    pacc = MFMA(pa1, b2v, pacc);
                    pacc = MFMA(pa2, b1v, pacc);
                    pacc = MFMA(pa1, b1v, pacc);
                }
            }
            if (q == 3 && s < T_) {    // Gm dump merged before loop-final sync
                #pragma unroll
                for (int i = 0; i < 4; ++i) {
                    Gm[w][quad * 4 + i][ln] = dg0[i];
                    Gm[w][16 + quad * 4 + i][ln] = dg1[i];
                }
            }
            __syncthreads();
        }

        // projection output: h_s @ pw^T + pb -> out column s-1
        if (doproj) {
            const int v = (jt >> 1) * 16 + ln;
            if (v < V_) {
                const double pbv = pbd[v];
                const int mtp = mh * 2 + tpj;
                #pragma unroll
                for (int i = 0; i < 4; ++i) {
                    const int m = mtp * 16 + quad * 4 + i;
                    const long idx = ((long)m * V_ + v) * T_ + (s - 1);
                    const float val = (float)((double)pacc[i] + pbv);
                    if (isf32) ((float*)outp)[idx] = val;
                    else       ((bf16_t*)outp)[idx] = (bf16_t)val;
                }
            }
        }

        if (s < T_) {
            // gate: one output per thread, all f64 (round-8 verbatim)
            {
                double R  = Gm[0][gm][gj] + Gm[4][gm][gj] + bbR;
                double Z  = Gm[1][gm][gj] + Gm[5][gm][gj] + bbZ;
                double NI = Gm[2][gm][gj] + Gm[6][gm][gj] + bbNI;
                double NH = Gm[3][gm][gj] + Gm[7][gm][gj] + bbNH;
                if (s == 0) { R += g0R; Z += g0Z; NI += g0NI; }
                const double r = 1.0 / (1.0 + exp(-R));
                const double z = 1.0 / (1.0 + exp(-Z));
                const double pre = NI + r * NH;
                const double n = 1.0 - 2.0 / (exp(2.0 * pre) + 1.0);   // tanh
                hreg = (1.0 - z) * n + z * hreg;
                const long oi = (long)(m0base + gm) * H_ + jg;
                // plain stores: stay cached in this XCD's L2 (readers are
                // same-XCD, sc0); drained to L2 by the syncthreads below.
                u16* ho = (u16*)(hsp + (long)((s + 1) & 1) * 3 * NF_);
                bfbits q1, q2, q3;
                q1.b = (bf16_t)(float)hreg;  double r1 = hreg - (double)(float)q1.b;
                q2.b = (bf16_t)(float)r1;    double r2 = r1 - (double)(float)q2.b;
                q3.b = (bf16_t)(float)r2;
                ho[oi] = q1.u;
                ho[NF_ + oi] = q2.u;
                ho[2 * NF_ + oi] = q3.u;
            }

            // per-mh barrier: parallel flag stores + ALL-wave poll, self-
            // release (no release sync; next-step q0-end barrier reconverges.
            // Safe: every wave passed this sync -> all A-buffer reads done).
            __syncthreads();          // drains all waves' h stores (vmcnt 0)
            if (tid == 0)
                __hip_atomic_store(myflag, s + 1, __ATOMIC_RELAXED,
                                   __HIP_MEMORY_SCOPE_AGENT);
            {
                int lim = 0;
                for (;;) {
                    int v = __hip_atomic_load(pollp, __ATOMIC_RELAXED,
                                              __HIP_MEMORY_SCOPE_AGENT);
                    if (__all(v >= s + 1)) break;
                    __builtin_amdgcn_s_sleep(1);
                    if (++lim > 100000000) break;      // failsafe: no hang
                }
            }
            if (s == 0) {   // swap to combined weights for s>=1
                #pragma unroll
                for (int n = 0; n < 8; ++n)
                    #pragma unroll
                    for (int sp = 0; sp < 3; ++sp)
                        Breg[n][sp] = *(const bf16x8*)(wpW + sp * 8192 + (par + 2 * n) * 512);
            }
        }
    }
}

// ---------------------------------------------------------------------------
extern "C" void kernel_launch(void* const* d_in, const int* in_sizes, int n_in,
                              void* d_out, int out_size, void* d_ws, size_t ws_size,
                              hipStream_t stream) {
    char* ws = (char*)d_ws;
    char*   barr = ws;                          // [0,40960): flags + xslot
    int*    flag = (int*)(ws + 40960);
    bf16_t* WB  = (bf16_t*)(ws + 41216);        // 6,291,456 B
    bf16_t* W0  = (bf16_t*)(ws + 6332672);      // 4,718,592 B
    bf16_t* PB  = (bf16_t*)(ws + 11051264);     //   458,752 B
    bf16_t* hsp = (bf16_t*)(ws + 11510016);     // 1,572,864 B (2 pp, linear)
    double* hf  = (double*)(ws + 13082880);     // 1,048,576 B (initial h)
    double* BB  = (double*)(ws + 14131456);     //    16,384 B
    double* pbd = (double*)(ws + 14147840);     //     1,024 B
    double* gi0 = (double*)(ws + 14148864);     //    12,288 B  (end ~13.5 MB)

    convert_kernel<<<1024, 256, 0, stream>>>(
        d_in[0], d_in[1], d_in[2], d_in[3], d_in[4], d_in[5], d_in[6], d_in[7],
        barr, flag, WB, W0, PB, hsp, hf, BB, pbd, gi0);

    gru_persist<<<256, 512, 0, stream>>>(
        WB, W0, PB, hsp, hf, BB, pbd, gi0, flag, barr, d_out);
}

// Round 9
// 1457.833 us; speedup vs baseline: 1.0189x; 1.0189x over previous
//
#include <hip/hip_runtime.h>
#include <hip/hip_bf16.h>
#include <math.h>

// CaptionModel: 200-step GRU (B=256,H=512) + projection V=100.
// Round-19 = round-17 (best, 1420us steady) + deferred projection stores:
//  the 4 scattered output dwords per proj-lane (stride 800B -> 1 line/lane,
//  ~256 HBM write transactions) were issued BEFORE the pre-flag
//  __syncthreads, whose vmcnt(0) drained them to retirement every step on
//  every proj block; the per-mh barrier then propagated that ~1-2k cy drain
//  to all 32 blocks. Now: values+indices computed before the gate phase
//  (pval[4]+idx0 in regs), stores issued AFTER the flag store -> they retire
//  under the poll wait and drain at the NEXT step's sync (free).
// r18's all-wave self-release poll REVERTED (steady 1439 vs 1420: poll
// traffic queued ahead of the flag store - r13 failure mode). r18's 32-bit
// convert indexing kept (convert-only).
// Everything else r17-verbatim: XCD-local L2 h-exchange (plain stores + sc0
// loads), counted per-quarter vmcnt staging, per-block flag lines + wave-0
// 32-lane poll + release sync.
// Ledger of measured-dead levers: r12 lc-swizzle/Gm-pad/static-proj (-4%),
// r13 arrival tree (-5%), r14 2 blocks/CU (Breg spill, -82%), r15 single
// vmcnt(0) (-5%), r17 flag barrier (0%), r18 self-release poll (-1.3%).
// Canary: absmax must be exactly 0.0078125.

typedef __bf16 bf16_t;
typedef __bf16 bf16x8 __attribute__((ext_vector_type(8)));
typedef float f32x4 __attribute__((ext_vector_type(4)));
typedef unsigned long long u64;
typedef unsigned short u16;
typedef unsigned int u32;

#define B_ 256
#define H_ 512
#define V_ 100
#define T_ 200
#define NF_ 131072              // B_*H_
#define SLAB_ 24576             // per (group,jt): 3 sp * 16 c * 16 r * 32 k
#define MFMA(a,b,c) __builtin_amdgcn_mfma_f32_16x16x32_bf16((a),(b),(c),0,0,0)

__device__ __forceinline__ float ld_in(const void* p, long i, int isf32) {
    return isf32 ? ((const float*)p)[i] : (float)((const bf16_t*)p)[i];
}

__device__ __forceinline__ bf16_t split_pick(double v, int sp) {
    bf16_t a = (bf16_t)(float)v;
    if (sp == 0) return a;
    double r1 = v - (double)(float)a;
    bf16_t b = (bf16_t)(float)r1;
    if (sp == 1) return b;
    double r2 = r1 - (double)(float)b;
    return (bf16_t)(float)r2;
}

union bfbits { __bf16 b; u16 u; };

// ---------------------------------------------------------------------------
// Canonical buffers (round-8 verbatim):
//  WB [4 grp][32 jt][3 sp][16 c][16 r][32 k]  grps: Rc, Zc, NI, NH
//  W0 [3 grp][32 jt][3 sp][16 c][16 r][32 k]  wh-only (s==0)
//  PB [7 vt][2 sp][16 c][16 r][32 k]
//  hsp linear [2 pp][3 sp][m 256][col 512];  BB [4][512] f64; gi0[1536] f64
__global__ __launch_bounds__(256) void convert_kernel(
    const void* __restrict__ feat, const void* __restrict__ embed,
    const void* __restrict__ wih,  const void* __restrict__ whh,
    const void* __restrict__ bih,  const void* __restrict__ bhh,
    const void* __restrict__ pw,   const void* __restrict__ pb,
    char* __restrict__ barr, int* __restrict__ flag,
    bf16_t* __restrict__ WB, bf16_t* __restrict__ W0, bf16_t* __restrict__ PB,
    bf16_t* __restrict__ hsp, double* __restrict__ hf,
    double* __restrict__ BB, double* __restrict__ pbd, double* __restrict__ gi0)
{
    // runtime dtype detection on feat (~N(0,1)): bf16 buffer -> low u16 of a
    // u32 is a plausible bf16 (~128/128); f32 -> mantissa bits (~15/128).
    __shared__ int s_cnt;
    if (threadIdx.x == 0) s_cnt = 0;
    __syncthreads();
    if (threadIdx.x < 128) {
        unsigned w = ((const unsigned*)feat)[threadIdx.x];
        unsigned e = (w >> 7) & 0xFFu;
        if (e >= 0x68u && e <= 0x85u) atomicAdd(&s_cnt, 1);
    }
    __syncthreads();
    const int isf32 = (s_cnt < 96) ? 1 : 0;
    if (blockIdx.x == 0) {
        if (threadIdx.x == 0) *flag = isf32;
        // zero barrier state: 256 flag lines (8 mh x 32 jt) + 8 xslot lines
        if (threadIdx.x < 256)
            *(int*)(barr + (size_t)threadIdx.x * 128) = 0;
        if (threadIdx.x < 8)
            *(int*)(barr + 32768 + (size_t)threadIdx.x * 128) = 0;
    }

    const u32 S0 = NF_;
    const u32 S1 = 3145728;      // WB elems
    const u32 S2 = 2359296;      // W0
    const u32 S3 = 114688;       // PB
    const u32 S4 = 2048;         // BB
    const u32 S5 = 100;          // pbd
    const u32 S6 = 1536;         // gi0
    const u32 TOT = S0 + S1 + S2 + S3 + S4 + S5 + S6;

    for (u32 g = blockIdx.x * 256u + threadIdx.x; g < TOT;
         g += (u32)gridDim.x * 256u) {
        u32 i = g;
        if (i < S0) {
            double v = (double)ld_in(feat, i, isf32);
            hf[i] = v;
            hsp[i] = split_pick(v, 0);
            hsp[NF_ + i] = split_pick(v, 1);
            hsp[2 * NF_ + i] = split_pick(v, 2);
            continue;
        }
        i -= S0;
        if (i < S1) {
            u32 slab = i / SLAB_;  u32 rem = i % SLAB_;
            u32 grp = slab >> 5, jt = slab & 31;
            u32 sp = rem / 8192; u32 r2 = rem % 8192;
            u32 c = r2 / 512, r = (r2 % 512) / 32, kk = r2 & 31;
            u32 n = jt * 16 + r, k = c * 32 + kk;
            double v;
            if (grp == 0)      v = (double)ld_in(wih, n * H_ + k, isf32) +
                                   (double)ld_in(whh, n * H_ + k, isf32);
            else if (grp == 1) v = (double)ld_in(wih, (512 + n) * H_ + k, isf32) +
                                   (double)ld_in(whh, (512 + n) * H_ + k, isf32);
            else if (grp == 2) v = (double)ld_in(wih, (1024 + n) * H_ + k, isf32);
            else               v = (double)ld_in(whh, (1024 + n) * H_ + k, isf32);
            WB[i] = split_pick(v, sp);
            continue;
        }
        i -= S1;
        if (i < S2) {
            u32 slab = i / SLAB_;  u32 rem = i % SLAB_;
            u32 grp = slab >> 5, jt = slab & 31;
            u32 sp = rem / 8192; u32 r2 = rem % 8192;
            u32 c = r2 / 512, r = (r2 % 512) / 32, kk = r2 & 31;
            u32 n = jt * 16 + r, k = c * 32 + kk;
            u32 row = (grp == 0) ? n : (grp == 1) ? (512 + n) : (1024 + n);
            W0[i] = split_pick((double)ld_in(whh, row * H_ + k, isf32), sp);
            continue;
        }
        i -= S2;
        if (i < S3) {
            u32 vt = i / 16384; u32 rem = i % 16384;
            u32 sp = rem / 8192; u32 r2 = rem % 8192;
            u32 c = r2 / 512, r = (r2 % 512) / 32, kk = r2 & 31;
            u32 v = vt * 16 + r;
            u32 k = c * 32 + kk;
            double val = (v < V_) ? (double)ld_in(pw, (long)(v * H_ + k), isf32) : 0.0;
            PB[i] = split_pick(val, sp);
            continue;
        }
        i -= S3;
        if (i < S4) {
            u32 grp = i / 512, j = i & 511;
            double v;
            if (grp == 0)      v = (double)ld_in(bih, j, isf32) + (double)ld_in(bhh, j, isf32);
            else if (grp == 1) v = (double)ld_in(bih, 512 + j, isf32) + (double)ld_in(bhh, 512 + j, isf32);
            else if (grp == 2) v = (double)ld_in(bih, 1024 + j, isf32);
            else               v = (double)ld_in(bhh, 1024 + j, isf32);
            BB[i] = v;
            continue;
        }
        i -= S4;
        if (i < S5) { pbd[i] = (double)ld_in(pb, i, isf32); continue; }
        i -= S5;
        if (i < S6) {
            double acc = 0.0;
            #pragma unroll 8
            for (u32 k = 0; k < H_; ++k)
                acc += (double)ld_in(embed, k, isf32) *
                       (double)ld_in(wih, i * H_ + k, isf32);
            gi0[i] = acc;
        }
    }
}

// per-quarter tied wait: ds_writes of these 6 regs depend on this asm's
// outputs, so they cannot be scheduled above it (consumers are memory ops).
#define WAITQ(N, s0, s1, s2, s3, s4, s5)                                   \
    asm volatile("s_waitcnt vmcnt(" #N ")"                                 \
                 : "+v"(s0), "+v"(s1), "+v"(s2), "+v"(s3), "+v"(s4),       \
                   "+v"(s5) :: "memory")

// ---------------------------------------------------------------------------
// Persistent: 256 blocks x 512 threads (8 waves = 2/SIMD), 1 block/CU.
// mh = physical XCD (s_getreg HW_REG_XCC_ID), jt = per-XCD atomic slot 0..31
// (exactly 32 blocks/XCD by pigeonhole: 1 block/CU, 32 CU/XCD). The whole
// h-exchange for an mh-group is XCD-local: plain stores (L2-cached),
// sc0 loads (L1-bypass, read own L2). Barrier: per-block flag lines +
// wave-0 32-lane parallel poll + release sync (r17). Proj output stores
// deferred past the flag store (retire under the poll wait).
__global__ __launch_bounds__(512, 2) void gru_persist(
    const bf16_t* __restrict__ WB, const bf16_t* __restrict__ W0,
    const bf16_t* __restrict__ PB,
    bf16_t* __restrict__ hsp,      // [2 pp][3 sp][NF_] linear
    const double* __restrict__ hf, // initial h (f64)
    const double* __restrict__ BB, const double* __restrict__ pbd,
    const double* __restrict__ gi0,
    const int* __restrict__ flag, char* __restrict__ barr,
    void* __restrict__ outp)
{
    __shared__ __align__(16) u64 Ad[2][3072];     // 49,152 B: A dbuf (2 quarters)
    __shared__ double Gm[8][32][16];              // 32,768 B
    __shared__ __align__(16) bf16_t PBl[16384];   // 32,768 B: proj B slab
    __shared__ int s_slot;
    // total ~114,696 B static LDS (gfx950: 160 KB/CU, 1 block/CU)

    const int tid = threadIdx.x;
    const int w = tid >> 6;
    const int g = w & 3;
    const int par = w >> 2;
    const int lane = tid & 63;
    const int ln = lane & 15;
    const int quad = lane >> 4;

    // physical XCD id (wave-uniform; m09-verified 0..7 on MI355X)
    unsigned xcc;
    asm volatile("s_getreg_b32 %0, hwreg(HW_REG_XCC_ID)" : "=s"(xcc));
    xcc &= 7u;
    if (tid == 0) {
        int* xslot = (int*)(barr + 32768 + (size_t)xcc * 128);
        s_slot = __hip_atomic_fetch_add(xslot, 1, __ATOMIC_RELAXED,
                                        __HIP_MEMORY_SCOPE_AGENT);
    }
    __syncthreads();
    const int jt = s_slot & 31;      // unique 0..31 within this XCD
    const int mh = (int)xcc;         // mh-group == XCD -> L2-local exchange
    const int m0base = mh * 32;
    const int isf32 = *flag;

    // barrier flag lines: per mh, 32 lines of 128 B
    int* const flagbase = (int*)(barr + (size_t)mh * 4096);
    int* const myflag   = flagbase + (size_t)jt * 32;
    int* const pollp    = flagbase + (size_t)(lane & 31) * 32;

    // gate-phase ownership + step-invariant hoists (round-8 verbatim)
    const int gm = tid >> 4;
    const int gj = tid & 15;
    const int jg = jt * 16 + gj;
    double hreg = hf[(long)(m0base + gm) * H_ + jg];
    const double bbR = BB[jg], bbZ = BB[512 + jg];
    const double bbNI = BB[1024 + jg], bbNH = BB[1536 + jg];
    const double g0R = gi0[jg], g0Z = gi0[512 + jg], g0NI = gi0[1024 + jg];

    // weight fragments in registers: Breg[n][sp], chunk c = par + 2n
    bf16x8 Breg[8][3];
    {
        const int gg = (g == 3) ? 2 : g;          // s==0 slab (g==2 unused)
        const bf16_t* wpre = W0 + (long)(gg * 32 + jt) * SLAB_ + ln * 32 + quad * 8;
        #pragma unroll
        for (int n = 0; n < 8; ++n)
            #pragma unroll
            for (int sp = 0; sp < 3; ++sp)
                Breg[n][sp] = *(const bf16x8*)(wpre + sp * 8192 + (par + 2 * n) * 512);
    }
    const bf16_t* wpW = WB + (long)(g * 32 + jt) * SLAB_ + ln * 32 + quad * 8;

    const int tpj = jt & 1;

    // one-time PB slab -> LDS, fragment-linear: chunk j (8 bf16) of c-block
    // goes to slot L(j) = (j&3)*16 + (j>>2), so the doproj read of lane L is
    // a dense 16B at PBl + h01*8192 + c*512 + L*8 (conflict-free b128).
    if (jt < 14) {
        const bf16_t* src = PB + (long)(jt >> 1) * 16384;
        #pragma unroll
        for (int it = 0; it < 4; ++it) {
            int cg = it * 512 + tid;              // 2048 16B-chunks total
            int h01 = cg >> 10, c = (cg >> 6) & 15, j = cg & 63;
            int L = (j & 3) * 16 + (j >> 2);
            *(bf16x8*)(PBl + h01 * 8192 + c * 512 + L * 8) =
                *(const bf16x8*)(src + cg * 8);
        }
    }

    // swizzled element offset for this lane's A-fragment reads (parity XOR
    // matches the dump lpos; r = ln recovered since x^((x&1)<<2) is injective)
    const int lf = (((ln ^ quad) ^ ((ln & 1) << 2)) | (quad << 4)) * 8;

    // step-invariant staging addresses: thread's 6 elements per quarter.
    // load pattern (coalesced 512B/wave) is round-8 verbatim.
    int soff[6]; int ldst[6];
    #pragma unroll
    for (int i = 0; i < 6; ++i) {
        int u = i * 512 + tid;
        int sp = u >> 10, row = (u >> 5) & 31, k64 = u & 31;
        soff[i] = sp * 32768 + (m0base + row) * 128 + k64;
        int lc = k64 >> 3, qd = (k64 & 7) >> 1, half = k64 & 1;
        int lpos = (((row & 15) ^ qd) ^ ((row & 1) << 2)) | (qd << 4);
        ldst[i] = sp * 1024 + lc * 256 + (row >> 4) * 128 + lpos * 2 + half;
    }
    __syncthreads();     // PBl staged before any use

    for (int s = 0; s <= T_; ++s) {
        const u64* hin64 = (const u64*)(hsp + (long)(s & 1) * 3 * NF_);
        const bool gemm = (s < T_) && !(s == 0 && g == 2);
        const bool doproj = (s >= 1 && jt < 14 && w == (s & 7));

        double dg0[4] = {0, 0, 0, 0}, dg1[4] = {0, 0, 0, 0};
        f32x4 pacc = {0.f, 0.f, 0.f, 0.f};

        // all 24 h-loads issued up-front via sc0 (L1-bypass, own-XCD L2 hit),
        // in quarter order; counted vmcnt waits below keep later quarters in
        // flight under earlier quarters' dump+MFMA (r11-style pipelining).
        u64 sreg[24];
        #pragma unroll
        for (int qq = 0; qq < 4; ++qq)
            #pragma unroll
            for (int i = 0; i < 6; ++i) {
                const u64* p = hin64 + (long)soff[i] + qq * 32;
                asm volatile("global_load_dwordx2 %0, %1, off sc0"
                             : "=v"(sreg[qq * 6 + i]) : "v"(p));
            }

        // dump quarter 0 -> buf0 (wait only its 6 loads: 18 may remain)
        WAITQ(18, sreg[0], sreg[1], sreg[2], sreg[3], sreg[4], sreg[5]);
        #pragma unroll
        for (int i = 0; i < 6; ++i) Ad[0][ldst[i]] = sreg[i];
        __syncthreads();

        #pragma unroll
        for (int q = 0; q < 4; ++q) {
            if (q < 3) {     // dump q+1 into the other buffer (overlaps compute)
                if (q == 0)
                    WAITQ(12, sreg[6], sreg[7], sreg[8], sreg[9], sreg[10], sreg[11]);
                else if (q == 1)
                    WAITQ(6, sreg[12], sreg[13], sreg[14], sreg[15], sreg[16], sreg[17]);
                else
                    WAITQ(0, sreg[18], sreg[19], sreg[20], sreg[21], sreg[22], sreg[23]);
                #pragma unroll
                for (int i = 0; i < 6; ++i)
                    Ad[(q + 1) & 1][ldst[i]] = sreg[(q + 1) * 6 + i];
            }
            const __bf16* Ab = (const __bf16*)(Ad[q & 1]);

            if (gemm) {
                #pragma unroll
                for (int t = 0; t < 2; ++t) {
                    const int lc = 2 * t + par;
                    const int n = 2 * q + t;
                    bf16x8 A0[3], A1[3];
                    #pragma unroll
                    for (int sp = 0; sp < 3; ++sp) {
                        A0[sp] = *(const bf16x8*)(Ab + sp * 4096 + lc * 1024 + lf);
                        A1[sp] = *(const bf16x8*)(Ab + sp * 4096 + lc * 1024 + 512 + lf);
                    }
                    f32x4 t0 = {0.f, 0.f, 0.f, 0.f};
                    t0 = MFMA(A0[0], Breg[n][2], t0);
                    t0 = MFMA(A0[1], Breg[n][1], t0);
                    t0 = MFMA(A0[2], Breg[n][0], t0);
                    t0 = MFMA(A0[0], Breg[n][1], t0);
                    t0 = MFMA(A0[1], Breg[n][0], t0);
                    t0 = MFMA(A0[0], Breg[n][0], t0);
                    f32x4 t1 = {0.f, 0.f, 0.f, 0.f};
                    t1 = MFMA(A1[0], Breg[n][2], t1);
                    t1 = MFMA(A1[1], Breg[n][1], t1);
                    t1 = MFMA(A1[2], Breg[n][0], t1);
                    t1 = MFMA(A1[0], Breg[n][1], t1);
                    t1 = MFMA(A1[1], Breg[n][0], t1);
                    t1 = MFMA(A1[0], Breg[n][0], t1);
                    #pragma unroll
                    for (int i = 0; i < 4; ++i) {
                        dg0[i] += (double)t0[i];
                        dg1[i] += (double)t1[i];
                    }
                }
            }
            if (doproj) {
                #pragma unroll
                for (int lc = 0; lc < 4; ++lc) {   // ascending c: bit-exact
                    const int c = q * 4 + lc;
                    bf16x8 pa1 = *(const bf16x8*)(Ab + 0 * 4096 + lc * 1024 + tpj * 512 + lf);
                    bf16x8 pa2 = *(const bf16x8*)(Ab + 1 * 4096 + lc * 1024 + tpj * 512 + lf);
                    bf16x8 b1v = *(const bf16x8*)(PBl + c * 512 + lane * 8);
                    bf16x8 b2v = *(const bf16x8*)(PBl + 8192 + c * 512 + lane * 8);
                    pacc = MFMA(pa1, b2v, pacc);
                    pacc = MFMA(pa2, b1v, pacc);
                    pacc = MFMA(pa1, b1v, pacc);
                }
            }
            if (q == 3 && s < T_) {    // Gm dump merged before loop-final sync
                #pragma unroll
                for (int i = 0; i < 4; ++i) {
                    Gm[w][quad * 4 + i][ln] = dg0[i];
                    Gm[w][16 + quad * 4 + i][ln] = dg1[i];
                }
            }
            __syncthreads();
        }

        // projection: compute values + base index now (registers only);
        // the 4 scattered stores are DEFERRED past the flag store so their
        // HBM retirement is not drained by this step's barrier.
        float pval[4];
        long pidx0 = 0;
        bool pwrite = false;
        if (doproj) {
            const int v = (jt >> 1) * 16 + ln;
            if (v < V_) {
                pwrite = true;
                const double pbv = pbd[v];
                const int mtp = mh * 2 + tpj;
                const int m0 = mtp * 16 + quad * 4;
                pidx0 = ((long)m0 * V_ + v) * T_ + (s - 1);
                #pragma unroll
                for (int i = 0; i < 4; ++i)
                    pval[i] = (float)((double)pacc[i] + pbv);
            }
        }

        if (s < T_) {
            // gate: one output per thread, all f64 (round-8 verbatim)
            {
                double R  = Gm[0][gm][gj] + Gm[4][gm][gj] + bbR;
                double Z  = Gm[1][gm][gj] + Gm[5][gm][gj] + bbZ;
                double NI = Gm[2][gm][gj] + Gm[6][gm][gj] + bbNI;
                double NH = Gm[3][gm][gj] + Gm[7][gm][gj] + bbNH;
                if (s == 0) { R += g0R; Z += g0Z; NI += g0NI; }
                const double r = 1.0 / (1.0 + exp(-R));
                const double z = 1.0 / (1.0 + exp(-Z));
                const double pre = NI + r * NH;
                const double n = 1.0 - 2.0 / (exp(2.0 * pre) + 1.0);   // tanh
                hreg = (1.0 - z) * n + z * hreg;
                const long oi = (long)(m0base + gm) * H_ + jg;
                // plain stores: stay cached in this XCD's L2 (readers are
                // same-XCD, sc0); drained to L2 by the syncthreads below.
                u16* ho = (u16*)(hsp + (long)((s + 1) & 1) * 3 * NF_);
                bfbits q1, q2, q3;
                q1.b = (bf16_t)(float)hreg;  double r1 = hreg - (double)(float)q1.b;
                q2.b = (bf16_t)(float)r1;    double r2 = r1 - (double)(float)q2.b;
                q3.b = (bf16_t)(float)r2;
                ho[oi] = q1.u;
                ho[NF_ + oi] = q2.u;
                ho[2 * NF_ + oi] = q3.u;
            }

            // per-mh barrier (r17): drain h stores, parallel flag stores,
            // deferred proj stores, wave-0 32-lane poll, release sync.
            __syncthreads();          // drains all waves' h stores (vmcnt 0)
            if (tid == 0)
                __hip_atomic_store(myflag, s + 1, __ATOMIC_RELAXED,
                                   __HIP_MEMORY_SCOPE_AGENT);
            if (pwrite) {             // retire under the poll wait
                #pragma unroll
                for (int i = 0; i < 4; ++i) {
                    const long idx = pidx0 + (long)i * (V_ * T_);
                    if (isf32) ((float*)outp)[idx] = pval[i];
                    else       ((bf16_t*)outp)[idx] = (bf16_t)pval[i];
                }
            }
            if (w == 0) {
                int lim = 0;
                for (;;) {
                    int v = (lane < 32)
                        ? __hip_atomic_load(pollp, __ATOMIC_RELAXED,
                                            __HIP_MEMORY_SCOPE_AGENT)
                        : 0x7fffffff;
                    if (__all(v >= s + 1)) break;
                    __builtin_amdgcn_s_sleep(1);
                    if (++lim > 100000000) break;      // failsafe: no hang
                }
            }
            __syncthreads();          // release all waves
            if (s == 0) {   // swap to combined weights for s>=1
                #pragma unroll
                for (int n = 0; n < 8; ++n)
                    #pragma unroll
                    for (int sp = 0; sp < 3; ++sp)
                        Breg[n][sp] = *(const bf16x8*)(wpW + sp * 8192 + (par + 2 * n) * 512);
            }
        } else if (pwrite) {
            // s == T_: final column stores; kernel-end drains them.
            #pragma unroll
            for (int i = 0; i < 4; ++i) {
                const long idx = pidx0 + (long)i * (V_ * T_);
                if (isf32) ((float*)outp)[idx] = pval[i];
                else       ((bf16_t*)outp)[idx] = (bf16_t)pval[i];
            }
        }
    }
}

// ---------------------------------------------------------------------------
extern "C" void kernel_launch(void* const* d_in, const int* in_sizes, int n_in,
                              void* d_out, int out_size, void* d_ws, size_t ws_size,
                              hipStream_t stream) {
    char* ws = (char*)d_ws;
    char*   barr = ws;                          // [0,40960): flags + xslot
    int*    flag = (int*)(ws + 40960);
    bf16_t* WB  = (bf16_t*)(ws + 41216);        // 6,291,456 B
    bf16_t* W0  = (bf16_t*)(ws + 6332672);      // 4,718,592 B
    bf16_t* PB  = (bf16_t*)(ws + 11051264);     //   458,752 B
    bf16_t* hsp = (bf16_t*)(ws + 11510016);     // 1,572,864 B (2 pp, linear)
    double* hf  = (double*)(ws + 13082880);     // 1,048,576 B (initial h)
    double* BB  = (double*)(ws + 14131456);     //    16,384 B
    double* pbd = (double*)(ws + 14147840);     //     1,024 B
    double* gi0 = (double*)(ws + 14148864);     //    12,288 B  (end ~13.5 MB)

    convert_kernel<<<1024, 256, 0, stream>>>(
        d_in[0], d_in[1], d_in[2], d_in[3], d_in[4], d_in[5], d_in[6], d_in[7],
        barr, flag, WB, W0, PB, hsp, hf, BB, pbd, gi0);

    gru_persist<<<256, 512, 0, stream>>>(
        WB, W0, PB, hsp, hf, BB, pbd, gi0, flag, barr, d_out);
}